// Round 1
// baseline (1120.650 us; speedup 1.0000x reference)
//
#include <hip/hip_runtime.h>

#define N_NODES 32000

__device__ __forceinline__ float leakyf(float v) { return v >= 0.f ? v : 0.1f * v; }

__global__ __launch_bounds__(256) void k_count(const int* __restrict__ dst, int* __restrict__ cnt, int E)
{
    int e = blockIdx.x * 256 + threadIdx.x;
    if (e < E) atomicAdd(&cnt[dst[e]], 1);
}

__global__ __launch_bounds__(1024) void k_scan(const int* __restrict__ cnt, int* __restrict__ rp, int n, int E)
{
    __shared__ int sh[1024];
    int t = threadIdx.x;
    int base = t * 32;
    int ls = 0;
#pragma unroll
    for (int i = 0; i < 32; ++i) { int idx = base + i; if (idx < n) ls += cnt[idx]; }
    sh[t] = ls;
    __syncthreads();
    for (int off = 1; off < 1024; off <<= 1) {
        int v = 0;
        if (t >= off) v = sh[t - off];
        __syncthreads();
        if (t >= off) sh[t] += v;
        __syncthreads();
    }
    int run = sh[t] - ls;   // exclusive prefix of this thread's chunk
#pragma unroll
    for (int i = 0; i < 32; ++i) {
        int idx = base + i;
        if (idx < n) { rp[idx] = run; run += cnt[idx]; }
    }
    if (t == 0) rp[n] = E;
}

__global__ __launch_bounds__(256) void k_place(const int* __restrict__ src, const int* __restrict__ dst,
                                               const int* __restrict__ rp, int* __restrict__ cur,
                                               int* __restrict__ cs, int E)
{
    int e = blockIdx.x * 256 + threadIdx.x;
    if (e < E) {
        int d = dst[e];
        int p = rp[d] + atomicAdd(&cur[d], 1);
        cs[p] = src[e];
    }
}

// C[m][o] = sum_k A[m][k] * W[o][k] + bias[o]   (A row-major [M,K], W row-major [OD,K])
// 64x64 block tile, 256 threads, 4x4 microtile, K_STEP=32, transposed padded LDS.
__global__ __launch_bounds__(256) void k_gemm(const float* __restrict__ A, const float* __restrict__ W,
                                              const float* __restrict__ bias, float* __restrict__ C,
                                              int K, int OD)
{
    __shared__ float As[32 * 68];   // [kk][row], stride 68 keeps 16B alignment, low conflicts
    __shared__ float Bs[32 * 68];
    const int bm = blockIdx.x * 64;
    const int bo = blockIdx.y * 64;
    const int t  = threadIdx.x;
    const int tx = t & 15, ty = t >> 4;
    const int lr = t >> 3;          // 0..31
    const int lc = (t & 7) * 4;     // 0..28
    const float* Ap = A + (bm + lr) * K + lc;
    const float* Wq = W + (bo + lr) * K + lc;
    float acc[4][4] = {};
    for (int k0 = 0; k0 < K; k0 += 32) {
        float4 a0 = *(const float4*)(Ap + k0);
        float4 a1 = *(const float4*)(Ap + k0 + 32 * K);
        float4 b0 = *(const float4*)(Wq + k0);
        float4 b1 = *(const float4*)(Wq + k0 + 32 * K);
        __syncthreads();
        As[(lc + 0) * 68 + lr] = a0.x; As[(lc + 1) * 68 + lr] = a0.y;
        As[(lc + 2) * 68 + lr] = a0.z; As[(lc + 3) * 68 + lr] = a0.w;
        As[(lc + 0) * 68 + lr + 32] = a1.x; As[(lc + 1) * 68 + lr + 32] = a1.y;
        As[(lc + 2) * 68 + lr + 32] = a1.z; As[(lc + 3) * 68 + lr + 32] = a1.w;
        Bs[(lc + 0) * 68 + lr] = b0.x; Bs[(lc + 1) * 68 + lr] = b0.y;
        Bs[(lc + 2) * 68 + lr] = b0.z; Bs[(lc + 3) * 68 + lr] = b0.w;
        Bs[(lc + 0) * 68 + lr + 32] = b1.x; Bs[(lc + 1) * 68 + lr + 32] = b1.y;
        Bs[(lc + 2) * 68 + lr + 32] = b1.z; Bs[(lc + 3) * 68 + lr + 32] = b1.w;
        __syncthreads();
#pragma unroll
        for (int kk = 0; kk < 32; ++kk) {
            float4 av = *(const float4*)&As[kk * 68 + ty * 4];
            float4 bv = *(const float4*)&Bs[kk * 68 + tx * 4];
            float a[4] = {av.x, av.y, av.z, av.w};
            float b[4] = {bv.x, bv.y, bv.z, bv.w};
#pragma unroll
            for (int i = 0; i < 4; ++i)
#pragma unroll
                for (int j = 0; j < 4; ++j)
                    acc[i][j] = fmaf(a[i], b[j], acc[i][j]);
        }
    }
    float4 bb = *(const float4*)&bias[bo + tx * 4];
    float bj[4] = {bb.x, bb.y, bb.z, bb.w};
#pragma unroll
    for (int i = 0; i < 4; ++i) {
        float4 o;
        o.x = acc[i][0] + bj[0];
        o.y = acc[i][1] + bj[1];
        o.z = acc[i][2] + bj[2];
        o.w = acc[i][3] + bj[3];
        *(float4*)&C[(bm + ty * 4 + i) * OD + bo + tx * 4] = o;
    }
}

// out[n] = relu(h[n] + sum_{e in CSR[n]} h[src_e]) ; eps=0 so self term is h[n]
template <int DD>
__global__ __launch_bounds__(256) void k_agg_relu(const float* __restrict__ h, const int* __restrict__ rp,
                                                  const int* __restrict__ cs, float* __restrict__ out)
{
    const int n = blockIdx.x;
    const int t = threadIdx.x;
    constexpr int R = DD / 256;
    float acc[R];
#pragma unroll
    for (int i = 0; i < R; ++i) acc[i] = h[n * DD + t + i * 256];
    const int beg = rp[n], end = rp[n + 1];
    for (int e = beg; e < end; ++e) {
        const float* hs = h + cs[e] * DD + t;
#pragma unroll
        for (int i = 0; i < R; ++i) acc[i] += hs[i * 256];
    }
#pragma unroll
    for (int i = 0; i < R; ++i) out[n * DD + t + i * 256] = fmaxf(acc[i], 0.f);
}

// sums[0..D) = column sums, sums[D..2D) = column sums of squares
__global__ __launch_bounds__(256) void k_bn_stats(const float* __restrict__ h, float* __restrict__ sums, int D)
{
    const int r0 = blockIdx.x * 64;
    const int t = threadIdx.x;
    for (int f = t; f < D; f += 256) {
        float s = 0.f, q = 0.f;
        for (int r = 0; r < 64; ++r) {
            float v = h[(r0 + r) * D + f];
            s += v;
            q = fmaf(v, v, q);
        }
        atomicAdd(&sums[f], s);
        atomicAdd(&sums[D + f], q);
    }
}

// ss[0..D) = scale, ss[D..2D) = shift
__global__ __launch_bounds__(512) void k_bn_finalize(const float* __restrict__ sums, const float* __restrict__ gam,
                                                     const float* __restrict__ bet, float* __restrict__ ss, int D)
{
    int t = threadIdx.x;
    if (t < D) {
        const float invN = 1.f / (float)N_NODES;
        float mu  = sums[t] * invN;
        float var = sums[D + t] * invN - mu * mu;
        float rs  = rsqrtf(var + 1e-5f);
        float sc  = gam[t] * rs;
        ss[t]     = sc;
        ss[D + t] = bet[t] - mu * sc;
    }
}

__global__ __launch_bounds__(256) void k_bn_apply(float* __restrict__ h, const float* __restrict__ ss, int D)
{
    int i = blockIdx.x * 256 + threadIdx.x;
    float4 v = ((float4*)h)[i];
    int c = (i * 4) & (D - 1);
    float4 sc = *(const float4*)&ss[c];
    float4 sh = *(const float4*)&ss[D + c];
    v.x = leakyf(fmaf(v.x, sc.x, sh.x));
    v.y = leakyf(fmaf(v.y, sc.y, sh.y));
    v.z = leakyf(fmaf(v.z, sc.z, sh.z));
    v.w = leakyf(fmaf(v.w, sc.w, sh.w));
    ((float4*)h)[i] = v;
}

// gp[b][f] += sum over 250 rows (8 chunks per batch of 2000 nodes); divided by 2000 in k_final
__global__ __launch_bounds__(256) void k_pool(const float* __restrict__ h, float* __restrict__ gp)
{
    int b = blockIdx.x, ch = blockIdx.y, t = threadIdx.x;
    int r0 = b * 2000 + ch * 250;
    float s = 0.f;
    for (int r = 0; r < 250; ++r) s += h[(r0 + r) * 256 + t];
    atomicAdd(&gp[b * 256 + t], s);
}

__global__ __launch_bounds__(64) void k_final(const float* __restrict__ gp, const float* __restrict__ Wp,
                                              const float* __restrict__ bp, float* __restrict__ out)
{
    __shared__ float lg[32];
    int t = threadIdx.x;
    if (t < 32) {
        int b = t >> 1, c = t & 1;
        float s = 0.f;
        for (int k = 0; k < 256; ++k) s = fmaf(gp[b * 256 + k], Wp[c * 256 + k], s);
        float o = s * (1.f / 2000.f) + bp[c];
        out[b * 2 + c] = o;
        lg[t] = o;
    }
    __syncthreads();
    if (t < 16) out[32 + t] = (lg[t * 2 + 1] > lg[t * 2]) ? 1.f : 0.f;
}

extern "C" void kernel_launch(void* const* d_in, const int* in_sizes, int n_in,
                              void* d_out, int out_size, void* d_ws, size_t ws_size,
                              hipStream_t stream)
{
    const float* x   = (const float*)d_in[0];
    const int*   ei  = (const int*)d_in[1];
    const float* W1  = (const float*)d_in[2];
    const float* b1  = (const float*)d_in[3];
    const float* W2  = (const float*)d_in[4];
    const float* b2  = (const float*)d_in[5];
    const float* W3  = (const float*)d_in[6];
    const float* b3  = (const float*)d_in[7];
    const float* g1  = (const float*)d_in[8];
    const float* be1 = (const float*)d_in[9];
    const float* g2  = (const float*)d_in[10];
    const float* be2 = (const float*)d_in[11];
    const float* g3  = (const float*)d_in[12];
    const float* be3 = (const float*)d_in[13];
    const float* Wp  = (const float*)d_in[14];
    const float* bp  = (const float*)d_in[15];
    float* out = (float*)d_out;

    const int E = in_sizes[1] / 2;
    const int* src = ei;
    const int* dst = ei + E;

    char* ws = (char*)d_ws;
    size_t off = 0;
    auto alloc = [&](size_t bytes) -> void* {
        void* p = ws + off;
        off = (off + bytes + 255) & ~(size_t)255;
        return p;
    };
    float* bufA = (float*)alloc((size_t)N_NODES * 512 * 4);
    float* bufB = (float*)alloc((size_t)N_NODES * 512 * 4);
    int*   cs   = (int*)alloc((size_t)E * 4);
    int*   rp   = (int*)alloc((size_t)(N_NODES + 1) * 4);
    int*   cnt  = (int*)alloc((size_t)N_NODES * 4);
    int*   cur  = (int*)alloc((size_t)N_NODES * 4);
    float* sums = (float*)alloc(1024 * 4);  // sum | sumsq (max D=512)
    float* ss   = (float*)alloc(1024 * 4);  // scale | shift
    float* gp   = (float*)alloc(16 * 256 * 4);

    hipMemsetAsync(cnt, 0, (size_t)N_NODES * 4, stream);
    hipMemsetAsync(cur, 0, (size_t)N_NODES * 4, stream);
    const int eb = (E + 255) / 256;
    k_count<<<eb, 256, 0, stream>>>(dst, cnt, E);
    k_scan<<<1, 1024, 0, stream>>>(cnt, rp, N_NODES, E);
    k_place<<<eb, 256, 0, stream>>>(src, dst, rp, cur, cs, E);

    // ---- layer 1: x[32000,256] -> h[32000,512] ----
    k_gemm<<<dim3(500, 8), 256, 0, stream>>>(x, W1, b1, bufA, 256, 512);
    k_agg_relu<512><<<N_NODES, 256, 0, stream>>>(bufA, rp, cs, bufB);
    hipMemsetAsync(sums, 0, 1024 * 4, stream);
    k_bn_stats<<<500, 256, 0, stream>>>(bufB, sums, 512);
    k_bn_finalize<<<1, 512, 0, stream>>>(sums, g1, be1, ss, 512);
    k_bn_apply<<<N_NODES * 512 / 4 / 256, 256, 0, stream>>>(bufB, ss, 512);

    // ---- layer 2: [32000,512] -> [32000,512] ----
    k_gemm<<<dim3(500, 8), 256, 0, stream>>>(bufB, W2, b2, bufA, 512, 512);
    k_agg_relu<512><<<N_NODES, 256, 0, stream>>>(bufA, rp, cs, bufB);
    hipMemsetAsync(sums, 0, 1024 * 4, stream);
    k_bn_stats<<<500, 256, 0, stream>>>(bufB, sums, 512);
    k_bn_finalize<<<1, 512, 0, stream>>>(sums, g2, be2, ss, 512);
    k_bn_apply<<<N_NODES * 512 / 4 / 256, 256, 0, stream>>>(bufB, ss, 512);

    // ---- layer 3: [32000,512] -> [32000,256] ----
    k_gemm<<<dim3(500, 4), 256, 0, stream>>>(bufB, W3, b3, bufA, 512, 256);
    k_agg_relu<256><<<N_NODES, 256, 0, stream>>>(bufA, rp, cs, bufB);
    hipMemsetAsync(sums, 0, 1024 * 4, stream);
    k_bn_stats<<<500, 256, 0, stream>>>(bufB, sums, 256);
    k_bn_finalize<<<1, 512, 0, stream>>>(sums, g3, be3, ss, 256);
    k_bn_apply<<<N_NODES * 256 / 4 / 256, 256, 0, stream>>>(bufB, ss, 256);

    // ---- pool + head ----
    hipMemsetAsync(gp, 0, 16 * 256 * 4, stream);
    k_pool<<<dim3(16, 8), 256, 0, stream>>>(bufB, gp);
    k_final<<<1, 64, 0, stream>>>(gp, Wp, bp, out);
}

// Round 2
// 566.608 us; speedup vs baseline: 1.9778x; 1.9778x over previous
//
#include <hip/hip_runtime.h>

#define N_NODES 32000
typedef unsigned short u16;
typedef unsigned int u32;
typedef __attribute__((ext_vector_type(8))) short bf16x8;
typedef __attribute__((ext_vector_type(4))) float f32x4;

__device__ __forceinline__ float leakyf(float v) { return v >= 0.f ? v : 0.1f * v; }
__device__ __forceinline__ u16 f2bf(float f) {
    u32 u = __float_as_uint(f);
    return (u16)((u + 0x7FFFu + ((u >> 16) & 1u)) >> 16);
}
__device__ __forceinline__ float bf2f(u16 h) { return __uint_as_float(((u32)h) << 16); }
__device__ __forceinline__ float bf_lo(u32 u) { return __uint_as_float(u << 16); }
__device__ __forceinline__ float bf_hi(u32 u) { return __uint_as_float(u & 0xFFFF0000u); }
__device__ __forceinline__ u32 pack2(float a, float b) { return (u32)f2bf(a) | ((u32)f2bf(b) << 16); }

__device__ __forceinline__ void gload16(const u16* g, u16* l) {
    __builtin_amdgcn_global_load_lds((const __attribute__((address_space(1))) void*)g,
                                     (__attribute__((address_space(3))) void*)l, 16, 0, 0);
}

// ---------------- CSR build ----------------
__global__ __launch_bounds__(256) void k_count(const int* __restrict__ dst, int* __restrict__ cnt, int E)
{
    int e = blockIdx.x * 256 + threadIdx.x;
    if (e < E) atomicAdd(&cnt[dst[e]], 1);
}

__global__ __launch_bounds__(1024) void k_scan(const int* __restrict__ cnt, int* __restrict__ rp, int n, int E)
{
    __shared__ int sh[1024];
    int t = threadIdx.x;
    int base = t * 32;
    int ls = 0;
#pragma unroll
    for (int i = 0; i < 32; ++i) { int idx = base + i; if (idx < n) ls += cnt[idx]; }
    sh[t] = ls;
    __syncthreads();
    for (int off = 1; off < 1024; off <<= 1) {
        int v = 0;
        if (t >= off) v = sh[t - off];
        __syncthreads();
        if (t >= off) sh[t] += v;
        __syncthreads();
    }
    int run = sh[t] - ls;
#pragma unroll
    for (int i = 0; i < 32; ++i) {
        int idx = base + i;
        if (idx < n) { rp[idx] = run; run += cnt[idx]; }
    }
    if (t == 0) rp[n] = E;
}

__global__ __launch_bounds__(256) void k_place(const int* __restrict__ src, const int* __restrict__ dst,
                                               const int* __restrict__ rp, int* __restrict__ cur,
                                               int* __restrict__ cs, int E)
{
    int e = blockIdx.x * 256 + threadIdx.x;
    if (e < E) {
        int d = dst[e];
        int p = rp[d] + atomicAdd(&cur[d], 1);
        cs[p] = src[e];
    }
}

// ---------------- fp32 -> bf16 ----------------
__global__ __launch_bounds__(256) void k_cvt(const float* __restrict__ in, u16* __restrict__ out)
{
    int i = blockIdx.x * 256 + threadIdx.x;
    float4 v = ((const float4*)in)[i];
    ushort4 o;
    o.x = f2bf(v.x); o.y = f2bf(v.y); o.z = f2bf(v.z); o.w = f2bf(v.w);
    ((ushort4*)out)[i] = o;
}

// ---------------- bf16 MFMA GEMM (m97 structure) ----------------
// C[m][o] = sum_k A[m][k]*W[o][k] + bias[o]; A [M,K] bf16 row-major, W [OD,K] bf16 row-major.
// 128x128 tile, BK=32, 256 thr = 4 waves (2x2), per-wave 64x64 = 4x4 frags of 16x16.
__global__ __launch_bounds__(256) void k_gemm_mfma(const u16* __restrict__ A, const u16* __restrict__ W,
                                                   const float* __restrict__ bias, u16* __restrict__ C,
                                                   int K, int OD)
{
    __shared__ u16 As[128 * 32];
    __shared__ u16 Bs[128 * 32];
    const int t = threadIdx.x;
    const int lane = t & 63;
    const int w = t >> 6;
    const int wr = w >> 1, wc = w & 1;
    const int bm = blockIdx.x * 128;
    const int bn = blockIdx.y * 128;

    // staging: chunk = issue*256 + w*64 + lane ; row=chunk>>2, kchunk=chunk&3 (8 bf16/chunk)
    const int c0 = w * 64 + lane;
    const int r0 = c0 >> 2, kc0 = (c0 & 3) * 8;
    const int c1 = c0 + 256;
    const int r1 = c1 >> 2, kc1 = (c1 & 3) * 8;
    const u16* gA0 = A + (size_t)(bm + r0) * K + kc0;
    const u16* gA1 = A + (size_t)(bm + r1) * K + kc1;
    const u16* gB0 = W + (size_t)(bn + r0) * K + kc0;
    const u16* gB1 = W + (size_t)(bn + r1) * K + kc1;
    u16* lA0 = As + w * 512;
    u16* lA1 = As + 2048 + w * 512;
    u16* lB0 = Bs + w * 512;
    u16* lB1 = Bs + 2048 + w * 512;

    f32x4 acc[4][4];
#pragma unroll
    for (int i = 0; i < 4; ++i)
#pragma unroll
        for (int j = 0; j < 4; ++j)
            acc[i][j] = (f32x4){0.f, 0.f, 0.f, 0.f};

    const int fr = lane & 15;
    const int ko = (lane >> 4) * 8;

    for (int k0 = 0; k0 < K; k0 += 32) {
        __syncthreads();
        gload16(gA0 + k0, lA0);
        gload16(gA1 + k0, lA1);
        gload16(gB0 + k0, lB0);
        gload16(gB1 + k0, lB1);
        asm volatile("s_waitcnt vmcnt(0)" ::: "memory");
        __syncthreads();
        bf16x8 af[4], bfv[4];
#pragma unroll
        for (int i = 0; i < 4; ++i)
            af[i] = *(const bf16x8*)&As[(wr * 64 + i * 16 + fr) * 32 + ko];
#pragma unroll
        for (int j = 0; j < 4; ++j)
            bfv[j] = *(const bf16x8*)&Bs[(wc * 64 + j * 16 + fr) * 32 + ko];
#pragma unroll
        for (int i = 0; i < 4; ++i)
#pragma unroll
            for (int j = 0; j < 4; ++j)
                acc[i][j] = __builtin_amdgcn_mfma_f32_16x16x32_bf16(af[i], bfv[j], acc[i][j], 0, 0, 0);
    }

    // epilogue: C/D map col=lane&15, row=(lane>>4)*4+r
    const int qr = (lane >> 4) * 4;
    float bcol[4];
#pragma unroll
    for (int j = 0; j < 4; ++j) bcol[j] = bias[bn + wc * 64 + j * 16 + fr];
#pragma unroll
    for (int i = 0; i < 4; ++i) {
#pragma unroll
        for (int r = 0; r < 4; ++r) {
            size_t row = (size_t)(bm + wr * 64 + i * 16 + qr + r);
#pragma unroll
            for (int j = 0; j < 4; ++j) {
                int col = bn + wc * 64 + j * 16 + fr;
                C[row * OD + col] = f2bf(acc[i][j][r] + bcol[j]);
            }
        }
    }
}

// ---------------- aggregate + self + relu (bf16) ----------------
// one wave per node; V = DD/64 bf16 per lane
template <int DD>
__global__ __launch_bounds__(256) void k_agg_relu(const u16* __restrict__ h, const int* __restrict__ rp,
                                                  const int* __restrict__ cs, u16* __restrict__ out)
{
    const int lane = threadIdx.x & 63;
    const int n = blockIdx.x * 4 + (threadIdx.x >> 6);
    constexpr int V = DD / 64;          // 8 or 4
    constexpr int VU = V / 2;           // uints per lane
    float acc[V];
    const u32* hp = (const u32*)(h + (size_t)n * DD) + lane * VU;
#pragma unroll
    for (int i = 0; i < VU; ++i) {
        u32 u = hp[i];
        acc[2 * i] = bf_lo(u);
        acc[2 * i + 1] = bf_hi(u);
    }
    const int beg = rp[n], end = rp[n + 1];
    for (int e = beg; e < end; ++e) {
        const u32* q = (const u32*)(h + (size_t)cs[e] * DD) + lane * VU;
#pragma unroll
        for (int i = 0; i < VU; ++i) {
            u32 u = q[i];
            acc[2 * i] += bf_lo(u);
            acc[2 * i + 1] += bf_hi(u);
        }
    }
    u32* op = (u32*)(out + (size_t)n * DD) + lane * VU;
#pragma unroll
    for (int i = 0; i < VU; ++i)
        op[i] = pack2(fmaxf(acc[2 * i], 0.f), fmaxf(acc[2 * i + 1], 0.f));
}

// ---------------- batchnorm ----------------
__global__ __launch_bounds__(256) void k_bn_stats(const u16* __restrict__ h, float* __restrict__ sums, int D)
{
    const int r0 = blockIdx.x * 64;
    const int t = threadIdx.x;
    for (int f = t; f < D; f += 256) {
        float s = 0.f, q = 0.f;
        for (int r = 0; r < 64; ++r) {
            float v = bf2f(h[(size_t)(r0 + r) * D + f]);
            s += v;
            q = fmaf(v, v, q);
        }
        atomicAdd(&sums[f], s);
        atomicAdd(&sums[D + f], q);
    }
}

__global__ __launch_bounds__(512) void k_bn_finalize(const float* __restrict__ sums, const float* __restrict__ gam,
                                                     const float* __restrict__ bet, float* __restrict__ ss, int D)
{
    int t = threadIdx.x;
    if (t < D) {
        const float invN = 1.f / (float)N_NODES;
        float mu  = sums[t] * invN;
        float var = sums[D + t] * invN - mu * mu;
        float rs  = rsqrtf(var + 1e-5f);
        float sc  = gam[t] * rs;
        ss[t]     = sc;
        ss[D + t] = bet[t] - mu * sc;
    }
}

// apply scale/shift + leaky, 8 bf16 per thread
__global__ __launch_bounds__(256) void k_bn_apply(u16* __restrict__ h, const float* __restrict__ ss, int D)
{
    int i = blockIdx.x * 256 + threadIdx.x;
    uint4 v = ((uint4*)h)[i];
    int c = (i * 8) & (D - 1);
    const float* sc = &ss[c];
    const float* sh = &ss[D + c];
    u32 r[4];
    u32 vv[4] = {v.x, v.y, v.z, v.w};
#pragma unroll
    for (int k = 0; k < 4; ++k) {
        float a = leakyf(fmaf(bf_lo(vv[k]), sc[2 * k], sh[2 * k]));
        float b = leakyf(fmaf(bf_hi(vv[k]), sc[2 * k + 1], sh[2 * k + 1]));
        r[k] = pack2(a, b);
    }
    ((uint4*)h)[i] = make_uint4(r[0], r[1], r[2], r[3]);
}

// ---------------- pool + head ----------------
__global__ __launch_bounds__(256) void k_pool(const u16* __restrict__ h, float* __restrict__ gp)
{
    int b = blockIdx.x, ch = blockIdx.y, t = threadIdx.x;
    int r0 = b * 2000 + ch * 250;
    float s = 0.f;
    for (int r = 0; r < 250; ++r) s += bf2f(h[(size_t)(r0 + r) * 256 + t]);
    atomicAdd(&gp[b * 256 + t], s);
}

__global__ __launch_bounds__(64) void k_final(const float* __restrict__ gp, const float* __restrict__ Wp,
                                              const float* __restrict__ bp, float* __restrict__ out)
{
    __shared__ float lg[32];
    int t = threadIdx.x;
    if (t < 32) {
        int b = t >> 1, c = t & 1;
        float s = 0.f;
        for (int k = 0; k < 256; ++k) s = fmaf(gp[b * 256 + k], Wp[c * 256 + k], s);
        float o = s * (1.f / 2000.f) + bp[c];
        out[b * 2 + c] = o;
        lg[t] = o;
    }
    __syncthreads();
    if (t < 16) out[32 + t] = (lg[t * 2 + 1] > lg[t * 2]) ? 1.f : 0.f;
}

extern "C" void kernel_launch(void* const* d_in, const int* in_sizes, int n_in,
                              void* d_out, int out_size, void* d_ws, size_t ws_size,
                              hipStream_t stream)
{
    const float* x   = (const float*)d_in[0];
    const int*   ei  = (const int*)d_in[1];
    const float* W1  = (const float*)d_in[2];
    const float* b1  = (const float*)d_in[3];
    const float* W2  = (const float*)d_in[4];
    const float* b2  = (const float*)d_in[5];
    const float* W3  = (const float*)d_in[6];
    const float* b3  = (const float*)d_in[7];
    const float* g1  = (const float*)d_in[8];
    const float* be1 = (const float*)d_in[9];
    const float* g2  = (const float*)d_in[10];
    const float* be2 = (const float*)d_in[11];
    const float* g3  = (const float*)d_in[12];
    const float* be3 = (const float*)d_in[13];
    const float* Wp  = (const float*)d_in[14];
    const float* bp  = (const float*)d_in[15];
    float* out = (float*)d_out;

    const int E = in_sizes[1] / 2;
    const int* src = ei;
    const int* dst = ei + E;

    char* ws = (char*)d_ws;
    size_t off = 0;
    auto alloc = [&](size_t bytes) -> void* {
        void* p = ws + off;
        off = (off + bytes + 255) & ~(size_t)255;
        return p;
    };
    u16*   bufA = (u16*)alloc((size_t)N_NODES * 512 * 2);
    u16*   bufB = (u16*)alloc((size_t)N_NODES * 512 * 2);
    u16*   xb   = (u16*)alloc((size_t)N_NODES * 256 * 2);
    u16*   w1b  = (u16*)alloc(512 * 256 * 2);
    u16*   w2b  = (u16*)alloc(512 * 512 * 2);
    u16*   w3b  = (u16*)alloc(256 * 512 * 2);
    int*   cs   = (int*)alloc((size_t)E * 4);
    int*   rp   = (int*)alloc((size_t)(N_NODES + 1) * 4);
    int*   cnt  = (int*)alloc((size_t)N_NODES * 4);
    int*   cur  = (int*)alloc((size_t)N_NODES * 4);
    float* sums = (float*)alloc(1024 * 4);
    float* ss   = (float*)alloc(1024 * 4);
    float* gp   = (float*)alloc(16 * 256 * 4);

    // CSR build
    hipMemsetAsync(cnt, 0, (size_t)N_NODES * 4, stream);
    hipMemsetAsync(cur, 0, (size_t)N_NODES * 4, stream);
    const int eb = (E + 255) / 256;
    k_count<<<eb, 256, 0, stream>>>(dst, cnt, E);
    k_scan<<<1, 1024, 0, stream>>>(cnt, rp, N_NODES, E);
    k_place<<<eb, 256, 0, stream>>>(src, dst, rp, cur, cs, E);

    // convert inputs/weights to bf16
    k_cvt<<<N_NODES * 256 / 4 / 256, 256, 0, stream>>>(x, xb);
    k_cvt<<<512 * 256 / 4 / 256, 256, 0, stream>>>(W1, w1b);
    k_cvt<<<512 * 512 / 4 / 256, 256, 0, stream>>>(W2, w2b);
    k_cvt<<<256 * 512 / 4 / 256, 256, 0, stream>>>(W3, w3b);

    // ---- layer 1: xb[32000,256] -> h[32000,512] ----
    k_gemm_mfma<<<dim3(250, 4), 256, 0, stream>>>(xb, w1b, b1, bufA, 256, 512);
    k_agg_relu<512><<<N_NODES / 4, 256, 0, stream>>>(bufA, rp, cs, bufB);
    hipMemsetAsync(sums, 0, 1024 * 4, stream);
    k_bn_stats<<<500, 256, 0, stream>>>(bufB, sums, 512);
    k_bn_finalize<<<1, 512, 0, stream>>>(sums, g1, be1, ss, 512);
    k_bn_apply<<<N_NODES * 512 / 8 / 256, 256, 0, stream>>>(bufB, ss, 512);

    // ---- layer 2: [32000,512] -> [32000,512] ----
    k_gemm_mfma<<<dim3(250, 4), 256, 0, stream>>>(bufB, w2b, b2, bufA, 512, 512);
    k_agg_relu<512><<<N_NODES / 4, 256, 0, stream>>>(bufA, rp, cs, bufB);
    hipMemsetAsync(sums, 0, 1024 * 4, stream);
    k_bn_stats<<<500, 256, 0, stream>>>(bufB, sums, 512);
    k_bn_finalize<<<1, 512, 0, stream>>>(sums, g2, be2, ss, 512);
    k_bn_apply<<<N_NODES * 512 / 8 / 256, 256, 0, stream>>>(bufB, ss, 512);

    // ---- layer 3: [32000,512] -> [32000,256] ----
    k_gemm_mfma<<<dim3(250, 2), 256, 0, stream>>>(bufB, w3b, b3, bufA, 512, 256);
    k_agg_relu<256><<<N_NODES / 4, 256, 0, stream>>>(bufA, rp, cs, bufB);
    hipMemsetAsync(sums, 0, 1024 * 4, stream);
    k_bn_stats<<<500, 256, 0, stream>>>(bufB, sums, 256);
    k_bn_finalize<<<1, 512, 0, stream>>>(sums, g3, be3, ss, 256);
    k_bn_apply<<<N_NODES * 256 / 8 / 256, 256, 0, stream>>>(bufB, ss, 256);

    // ---- pool + head ----
    hipMemsetAsync(gp, 0, 16 * 256 * 4, stream);
    k_pool<<<dim3(16, 8), 256, 0, stream>>>(bufB, gp);
    k_final<<<1, 64, 0, stream>>>(gp, Wp, bp, out);
}

// Round 3
// 492.929 us; speedup vs baseline: 2.2735x; 1.1495x over previous
//
#include <hip/hip_runtime.h>
#include <type_traits>

#define N_NODES 32000
typedef unsigned short u16;
typedef unsigned int u32;
typedef __attribute__((ext_vector_type(8))) short bf16x8;
typedef __attribute__((ext_vector_type(4))) float f32x4;

__device__ __forceinline__ float leakyf(float v) { return v >= 0.f ? v : 0.1f * v; }
__device__ __forceinline__ u16 f2bf(float f) {
    u32 u = __float_as_uint(f);
    return (u16)((u + 0x7FFFu + ((u >> 16) & 1u)) >> 16);
}
__device__ __forceinline__ float bf2f(u16 h) { return __uint_as_float(((u32)h) << 16); }
__device__ __forceinline__ float bf_lo(u32 u) { return __uint_as_float(u << 16); }
__device__ __forceinline__ float bf_hi(u32 u) { return __uint_as_float(u & 0xFFFF0000u); }
__device__ __forceinline__ u32 pack2(float a, float b) { return (u32)f2bf(a) | ((u32)f2bf(b) << 16); }

__device__ __forceinline__ void gload16(const u16* g, u16* l) {
    __builtin_amdgcn_global_load_lds((const __attribute__((address_space(1))) void*)g,
                                     (__attribute__((address_space(3))) void*)l, 16, 0, 0);
}

// ---------------- CSR build ----------------
__global__ __launch_bounds__(256) void k_count(const int* __restrict__ dst, int* __restrict__ cnt, int E)
{
    int e = blockIdx.x * 256 + threadIdx.x;
    if (e < E) atomicAdd(&cnt[dst[e]], 1);
}

__global__ __launch_bounds__(1024) void k_scan(const int* __restrict__ cnt, int* __restrict__ rp, int n, int E)
{
    __shared__ int sh[1024];
    int t = threadIdx.x;
    int base = t * 32;
    int ls = 0;
#pragma unroll
    for (int i = 0; i < 32; ++i) { int idx = base + i; if (idx < n) ls += cnt[idx]; }
    sh[t] = ls;
    __syncthreads();
    for (int off = 1; off < 1024; off <<= 1) {
        int v = 0;
        if (t >= off) v = sh[t - off];
        __syncthreads();
        if (t >= off) sh[t] += v;
        __syncthreads();
    }
    int run = sh[t] - ls;
#pragma unroll
    for (int i = 0; i < 32; ++i) {
        int idx = base + i;
        if (idx < n) { rp[idx] = run; run += cnt[idx]; }
    }
    if (t == 0) rp[n] = E;
}

__global__ __launch_bounds__(256) void k_place(const int* __restrict__ src, const int* __restrict__ dst,
                                               const int* __restrict__ rp, int* __restrict__ cur,
                                               int* __restrict__ cs, int E)
{
    int e = blockIdx.x * 256 + threadIdx.x;
    if (e < E) {
        int d = dst[e];
        int p = rp[d] + atomicAdd(&cur[d], 1);
        cs[p] = src[e];
    }
}

// ---------------- fp32 -> bf16 ----------------
__global__ __launch_bounds__(256) void k_cvt(const float* __restrict__ in, u16* __restrict__ out)
{
    int i = blockIdx.x * 256 + threadIdx.x;
    float4 v = ((const float4*)in)[i];
    ushort4 o;
    o.x = f2bf(v.x); o.y = f2bf(v.y); o.z = f2bf(v.z); o.w = f2bf(v.w);
    ((ushort4*)out)[i] = o;
}

// ---------------- bf16 MFMA GEMM (m97 structure) ----------------
// C[m][o] = sum_k A[m][k]*W[o][k] + biasmul*bias[o]; optional relu; biasmul=(deg+1) if DEGB.
template <bool RELU, bool DEGB>
__global__ __launch_bounds__(256) void k_gemm_mfma(const u16* __restrict__ A, const u16* __restrict__ W,
                                                   const float* __restrict__ bias, const int* __restrict__ rp,
                                                   u16* __restrict__ C, int K, int OD)
{
    __shared__ u16 As[128 * 32];
    __shared__ u16 Bs[128 * 32];
    const int t = threadIdx.x;
    const int lane = t & 63;
    const int w = t >> 6;
    const int wr = w >> 1, wc = w & 1;
    const int bm = blockIdx.x * 128;
    const int bn = blockIdx.y * 128;

    const int c0 = w * 64 + lane;
    const int r0 = c0 >> 2, kc0 = (c0 & 3) * 8;
    const int c1 = c0 + 256;
    const int r1 = c1 >> 2, kc1 = (c1 & 3) * 8;
    const u16* gA0 = A + (size_t)(bm + r0) * K + kc0;
    const u16* gA1 = A + (size_t)(bm + r1) * K + kc1;
    const u16* gB0 = W + (size_t)(bn + r0) * K + kc0;
    const u16* gB1 = W + (size_t)(bn + r1) * K + kc1;
    u16* lA0 = As + w * 512;
    u16* lA1 = As + 2048 + w * 512;
    u16* lB0 = Bs + w * 512;
    u16* lB1 = Bs + 2048 + w * 512;

    f32x4 acc[4][4];
#pragma unroll
    for (int i = 0; i < 4; ++i)
#pragma unroll
        for (int j = 0; j < 4; ++j)
            acc[i][j] = (f32x4){0.f, 0.f, 0.f, 0.f};

    const int fr = lane & 15;
    const int ko = (lane >> 4) * 8;

    for (int k0 = 0; k0 < K; k0 += 32) {
        __syncthreads();
        gload16(gA0 + k0, lA0);
        gload16(gA1 + k0, lA1);
        gload16(gB0 + k0, lB0);
        gload16(gB1 + k0, lB1);
        asm volatile("s_waitcnt vmcnt(0)" ::: "memory");
        __syncthreads();
        bf16x8 af[4], bfv[4];
#pragma unroll
        for (int i = 0; i < 4; ++i)
            af[i] = *(const bf16x8*)&As[(wr * 64 + i * 16 + fr) * 32 + ko];
#pragma unroll
        for (int j = 0; j < 4; ++j)
            bfv[j] = *(const bf16x8*)&Bs[(wc * 64 + j * 16 + fr) * 32 + ko];
#pragma unroll
        for (int i = 0; i < 4; ++i)
#pragma unroll
            for (int j = 0; j < 4; ++j)
                acc[i][j] = __builtin_amdgcn_mfma_f32_16x16x32_bf16(af[i], bfv[j], acc[i][j], 0, 0, 0);
    }

    // epilogue: C/D map col=lane&15, row=(lane>>4)*4+r
    const int qr = (lane >> 4) * 4;
    float bcol[4];
#pragma unroll
    for (int j = 0; j < 4; ++j) bcol[j] = bias[bn + wc * 64 + j * 16 + fr];
#pragma unroll
    for (int i = 0; i < 4; ++i) {
#pragma unroll
        for (int r = 0; r < 4; ++r) {
            int row = bm + wr * 64 + i * 16 + qr + r;
            float bm_ = 1.f;
            if (DEGB) bm_ = (float)(rp[row + 1] - rp[row]) + 1.f;
#pragma unroll
            for (int j = 0; j < 4; ++j) {
                int col = bn + wc * 64 + j * 16 + fr;
                float o = acc[i][j][r] + bm_ * bcol[j];
                if (RELU) o = fmaxf(o, 0.f);
                C[(size_t)row * OD + col] = f2bf(o);
            }
        }
    }
}

// ---------------- aggregate + self (+relu) (bf16), edge loop unrolled x4 ----------------
template <int DD, bool RELU>
__global__ __launch_bounds__(256) void k_agg(const u16* __restrict__ h, const int* __restrict__ rp,
                                             const int* __restrict__ cs, u16* __restrict__ out)
{
    constexpr int VU = DD / 128;               // u32 per lane: 2 (DD=256) or 4 (DD=512)
    using LT = typename std::conditional<VU == 4, uint4, uint2>::type;
    const int lane = threadIdx.x & 63;
    const int n = blockIdx.x * 4 + (threadIdx.x >> 6);
    const u32* hb = (const u32*)h + (size_t)lane * VU;
    const size_t rs = DD / 2;                  // row stride in u32

    float acc[2 * VU];
    {
        LT v = *(const LT*)(hb + (size_t)n * rs);
        const u32* vp = (const u32*)&v;
#pragma unroll
        for (int i = 0; i < VU; ++i) { acc[2 * i] = bf_lo(vp[i]); acc[2 * i + 1] = bf_hi(vp[i]); }
    }
    const int beg = rp[n], end = rp[n + 1];
    int e = beg;
    const int end4 = beg + ((end - beg) & ~3);
    for (; e < end4; e += 4) {
        int s0 = cs[e], s1 = cs[e + 1], s2 = cs[e + 2], s3 = cs[e + 3];
        LT v0 = *(const LT*)(hb + (size_t)s0 * rs);
        LT v1 = *(const LT*)(hb + (size_t)s1 * rs);
        LT v2 = *(const LT*)(hb + (size_t)s2 * rs);
        LT v3 = *(const LT*)(hb + (size_t)s3 * rs);
        const u32* p0 = (const u32*)&v0;
        const u32* p1 = (const u32*)&v1;
        const u32* p2 = (const u32*)&v2;
        const u32* p3 = (const u32*)&v3;
#pragma unroll
        for (int i = 0; i < VU; ++i) {
            acc[2 * i]     += bf_lo(p0[i]) + bf_lo(p1[i]) + bf_lo(p2[i]) + bf_lo(p3[i]);
            acc[2 * i + 1] += bf_hi(p0[i]) + bf_hi(p1[i]) + bf_hi(p2[i]) + bf_hi(p3[i]);
        }
    }
    for (; e < end; ++e) {
        LT v = *(const LT*)(hb + (size_t)cs[e] * rs);
        const u32* vp = (const u32*)&v;
#pragma unroll
        for (int i = 0; i < VU; ++i) { acc[2 * i] += bf_lo(vp[i]); acc[2 * i + 1] += bf_hi(vp[i]); }
    }
    u32* op = (u32*)out + (size_t)n * rs + lane * VU;
#pragma unroll
    for (int i = 0; i < VU; ++i) {
        float a = acc[2 * i], b = acc[2 * i + 1];
        if (RELU) { a = fmaxf(a, 0.f); b = fmaxf(b, 0.f); }
        op[i] = pack2(a, b);
    }
}

// ---------------- batchnorm ----------------
__global__ __launch_bounds__(256) void k_bn_stats(const u16* __restrict__ h, float* __restrict__ sums, int D)
{
    const int r0 = blockIdx.x * 64;
    const int t = threadIdx.x;
    for (int f = t; f < D; f += 256) {
        float s = 0.f, q = 0.f;
        for (int r = 0; r < 64; ++r) {
            float v = bf2f(h[(size_t)(r0 + r) * D + f]);
            s += v;
            q = fmaf(v, v, q);
        }
        atomicAdd(&sums[f], s);
        atomicAdd(&sums[D + f], q);
    }
}

__global__ __launch_bounds__(512) void k_bn_finalize(const float* __restrict__ sums, const float* __restrict__ gam,
                                                     const float* __restrict__ bet, float* __restrict__ ss, int D)
{
    int t = threadIdx.x;
    if (t < D) {
        const float invN = 1.f / (float)N_NODES;
        float mu  = sums[t] * invN;
        float var = sums[D + t] * invN - mu * mu;
        float rs  = rsqrtf(var + 1e-5f);
        float sc  = gam[t] * rs;
        ss[t]     = sc;
        ss[D + t] = bet[t] - mu * sc;
    }
}

__global__ __launch_bounds__(256) void k_bn_apply(u16* __restrict__ h, const float* __restrict__ ss, int D)
{
    int i = blockIdx.x * 256 + threadIdx.x;
    uint4 v = ((uint4*)h)[i];
    int c = (i * 8) & (D - 1);
    const float* sc = &ss[c];
    const float* sh = &ss[D + c];
    u32 r[4];
    u32 vv[4] = {v.x, v.y, v.z, v.w};
#pragma unroll
    for (int k = 0; k < 4; ++k) {
        float a = leakyf(fmaf(bf_lo(vv[k]), sc[2 * k], sh[2 * k]));
        float b = leakyf(fmaf(bf_hi(vv[k]), sc[2 * k + 1], sh[2 * k + 1]));
        r[k] = pack2(a, b);
    }
    ((uint4*)h)[i] = make_uint4(r[0], r[1], r[2], r[3]);
}

// ---------------- pool + head ----------------
__global__ __launch_bounds__(256) void k_pool(const u16* __restrict__ h, float* __restrict__ gp)
{
    int b = blockIdx.x, ch = blockIdx.y, t = threadIdx.x;
    int r0 = b * 2000 + ch * 250;
    float s = 0.f;
    for (int r = 0; r < 250; ++r) s += bf2f(h[(size_t)(r0 + r) * 256 + t]);
    atomicAdd(&gp[b * 256 + t], s);
}

__global__ __launch_bounds__(64) void k_final(const float* __restrict__ gp, const float* __restrict__ Wp,
                                              const float* __restrict__ bp, float* __restrict__ out)
{
    __shared__ float lg[32];
    int t = threadIdx.x;
    if (t < 32) {
        int b = t >> 1, c = t & 1;
        float s = 0.f;
        for (int k = 0; k < 256; ++k) s = fmaf(gp[b * 256 + k], Wp[c * 256 + k], s);
        float o = s * (1.f / 2000.f) + bp[c];
        out[b * 2 + c] = o;
        lg[t] = o;
    }
    __syncthreads();
    if (t < 16) out[32 + t] = (lg[t * 2 + 1] > lg[t * 2]) ? 1.f : 0.f;
}

extern "C" void kernel_launch(void* const* d_in, const int* in_sizes, int n_in,
                              void* d_out, int out_size, void* d_ws, size_t ws_size,
                              hipStream_t stream)
{
    const float* x   = (const float*)d_in[0];
    const int*   ei  = (const int*)d_in[1];
    const float* W1  = (const float*)d_in[2];
    const float* b1  = (const float*)d_in[3];
    const float* W2  = (const float*)d_in[4];
    const float* b2  = (const float*)d_in[5];
    const float* W3  = (const float*)d_in[6];
    const float* b3  = (const float*)d_in[7];
    const float* g1  = (const float*)d_in[8];
    const float* be1 = (const float*)d_in[9];
    const float* g2  = (const float*)d_in[10];
    const float* be2 = (const float*)d_in[11];
    const float* g3  = (const float*)d_in[12];
    const float* be3 = (const float*)d_in[13];
    const float* Wp  = (const float*)d_in[14];
    const float* bp  = (const float*)d_in[15];
    float* out = (float*)d_out;

    const int E = in_sizes[1] / 2;
    const int* src = ei;
    const int* dst = ei + E;

    char* ws = (char*)d_ws;
    size_t off = 0;
    auto alloc = [&](size_t bytes) -> void* {
        void* p = ws + off;
        off = (off + bytes + 255) & ~(size_t)255;
        return p;
    };
    u16*   bufA = (u16*)alloc((size_t)N_NODES * 512 * 2);
    u16*   bufB = (u16*)alloc((size_t)N_NODES * 512 * 2);
    u16*   xb   = (u16*)alloc((size_t)N_NODES * 256 * 2);
    u16*   w1b  = (u16*)alloc(512 * 256 * 2);
    u16*   w2b  = (u16*)alloc(512 * 512 * 2);
    u16*   w3b  = (u16*)alloc(256 * 512 * 2);
    int*   cs   = (int*)alloc((size_t)E * 4);
    int*   rp   = (int*)alloc((size_t)(N_NODES + 1) * 4);
    int*   cnt  = (int*)alloc((size_t)N_NODES * 4);
    int*   cur  = (int*)alloc((size_t)N_NODES * 4);
    float* sums = (float*)alloc(1024 * 4);
    float* ss   = (float*)alloc(1024 * 4);
    float* gp   = (float*)alloc(16 * 256 * 4);

    // CSR build
    hipMemsetAsync(cnt, 0, (size_t)N_NODES * 4, stream);
    hipMemsetAsync(cur, 0, (size_t)N_NODES * 4, stream);
    const int eb = (E + 255) / 256;
    k_count<<<eb, 256, 0, stream>>>(dst, cnt, E);
    k_scan<<<1, 1024, 0, stream>>>(cnt, rp, N_NODES, E);
    k_place<<<eb, 256, 0, stream>>>(src, dst, rp, cur, cs, E);

    // convert inputs/weights to bf16
    k_cvt<<<N_NODES * 256 / 4 / 256, 256, 0, stream>>>(x, xb);
    k_cvt<<<512 * 256 / 4 / 256, 256, 0, stream>>>(W1, w1b);
    k_cvt<<<512 * 512 / 4 / 256, 256, 0, stream>>>(W2, w2b);
    k_cvt<<<256 * 512 / 4 / 256, 256, 0, stream>>>(W3, w3b);

    // ---- layer 1 (linearity trick): s = x + sum_src x  (256-wide gather),
    //      z1 = relu(s@W1' + (deg+1)*b1) fused in GEMM ----
    k_agg<256, false><<<N_NODES / 4, 256, 0, stream>>>(xb, rp, cs, bufA);
    k_gemm_mfma<true, true><<<dim3(250, 4), 256, 0, stream>>>(bufA, w1b, b1, rp, bufB, 256, 512);
    hipMemsetAsync(sums, 0, 1024 * 4, stream);
    k_bn_stats<<<500, 256, 0, stream>>>(bufB, sums, 512);
    k_bn_finalize<<<1, 512, 0, stream>>>(sums, g1, be1, ss, 512);
    k_bn_apply<<<N_NODES * 512 / 8 / 256, 256, 0, stream>>>(bufB, ss, 512);

    // ---- layer 2: GEMM then 512-wide agg+relu ----
    k_gemm_mfma<false, false><<<dim3(250, 4), 256, 0, stream>>>(bufB, w2b, b2, rp, bufA, 512, 512);
    k_agg<512, true><<<N_NODES / 4, 256, 0, stream>>>(bufA, rp, cs, bufB);
    hipMemsetAsync(sums, 0, 1024 * 4, stream);
    k_bn_stats<<<500, 256, 0, stream>>>(bufB, sums, 512);
    k_bn_finalize<<<1, 512, 0, stream>>>(sums, g2, be2, ss, 512);
    k_bn_apply<<<N_NODES * 512 / 8 / 256, 256, 0, stream>>>(bufB, ss, 512);

    // ---- layer 3: GEMM (512->256) then 256-wide agg+relu ----
    k_gemm_mfma<false, false><<<dim3(250, 2), 256, 0, stream>>>(bufB, w3b, b3, rp, bufA, 512, 256);
    k_agg<256, true><<<N_NODES / 4, 256, 0, stream>>>(bufA, rp, cs, bufB);
    hipMemsetAsync(sums, 0, 1024 * 4, stream);
    k_bn_stats<<<500, 256, 0, stream>>>(bufB, sums, 256);
    k_bn_finalize<<<1, 512, 0, stream>>>(sums, g3, be3, ss, 256);
    k_bn_apply<<<N_NODES * 256 / 8 / 256, 256, 0, stream>>>(bufB, ss, 256);

    // ---- pool + head ----
    hipMemsetAsync(gp, 0, 16 * 256 * 4, stream);
    k_pool<<<dim3(16, 8), 256, 0, stream>>>(bufB, gp);
    k_final<<<1, 64, 0, stream>>>(gp, Wp, bp, out);
}